// Round 17
// baseline (404.452 us; speedup 1.0000x reference)
//
#include <hip/hip_runtime.h>
#include <hip/hip_bf16.h>
#include <math.h>

// Problem constants
#define BSZ 8
#define LSEQ 512
#define ENC_IN 7
#define D_MODEL 768
#define D_INNER 1536
#define DT_RANK 48
#define N_STATE 16
#define K_CONV 4
#define E_LAYERS 2
#define C_OUT 7
#define PRED_LEN 96
#define EPSV 1e-5f
#define XN 80
#define KSPLIT 4

#define ROWS (BSZ*LSEQ)            // 4096
#define NC 16                      // scan chunks
#define CL (LSEQ/NC)               // 32 steps per chunk
#define NTILE (LSEQ/16)            // 32 16-step tiles per batch
#define LOG2E 1.44269504088896f
#define DHALF (D_INNER/2)          // 768
// packed in_w geometry: 24 panels x 24 ksteps x 8 frags x 64 lanes x 8 elems
#define INP_PANELS (2*D_INNER/128)     // 24
#define INP_KSTEPS (D_MODEL/32)        // 24
#define INP_LAYER  (INP_PANELS*INP_KSTEPS*8*64*8)   // 2359296
// packed out_w geometry: 12 panels x 48 ksteps x 4 frags x 64 lanes x 8 elems
#define OUTP_PANELS (D_MODEL/64)       // 12
#define OUTP_KSTEPS (D_INNER/32)       // 48
#define OUTP_LAYER  (OUTP_PANELS*OUTP_KSTEPS*4*64*8)  // 1179648

typedef __bf16 bf16x8 __attribute__((ext_vector_type(8)));
typedef float  f32x4  __attribute__((ext_vector_type(4)));

__device__ __forceinline__ float fexp2(float x) {
    float r;
    asm("v_exp_f32 %0, %1" : "=v"(r) : "v"(x));
    return r;
}
__device__ __forceinline__ float softplusf(float v) {
    return fmaxf(v, 0.f) + log1pf(__expf(-fabsf(v)));
}
__device__ __forceinline__ void glds16(const char* g, char* l) {
    __builtin_amdgcn_global_load_lds((const __attribute__((address_space(1))) unsigned int*)g,
                                     (__attribute__((address_space(3))) unsigned int*)l, 16, 0, 0);
}

// ---------------------------------------------------------------- utilities
__device__ __forceinline__ float block_sum(float v, float* tmp) {
    #pragma unroll
    for (int off = 32; off > 0; off >>= 1) v += __shfl_down(v, off);
    int lane = threadIdx.x & 63, wid = threadIdx.x >> 6;
    __syncthreads();
    if (lane == 0) tmp[wid] = v;
    __syncthreads();
    return tmp[0] + tmp[1] + tmp[2] + tmp[3];
}

// ---------------------------------------------------------------- single fused prologue: cvt xpw/dtw + pack inw/outw
__global__ __launch_bounds__(256) void prep_all(const float* __restrict__ xpw,
                                                const float* __restrict__ dtw,
                                                const float* __restrict__ inw,
                                                const float* __restrict__ outw,
                                                __hip_bfloat16* __restrict__ xpw_bf,
                                                __hip_bfloat16* __restrict__ dtw_bf,
                                                __hip_bfloat16* __restrict__ inwp,
                                                __hip_bfloat16* __restrict__ outwp) {
    const int N3 = E_LAYERS*XN*D_INNER;
    const int N4 = E_LAYERS*D_INNER*64;
    const int NPI = E_LAYERS*INP_LAYER/8;
    const int NPO = E_LAYERS*OUTP_LAYER/8;
    int i = blockIdx.x*256 + threadIdx.x;
    if (i < N3) {
        xpw_bf[i] = __float2bfloat16(xpw[i]);
    } else if (i < N3+N4) {
        int j = i - N3;
        int r = j >> 6, c = j & 63;
        dtw_bf[j] = __float2bfloat16(c < DT_RANK ? dtw[r*DT_RANK + c] : 0.f);
    } else if (i < N3+N4+NPI) {
        int j = i - N3 - N4;
        const int PER_LAYER = INP_LAYER/8;
        int e2 = j / PER_LAYER;
        int r  = j % PER_LAYER;
        int l  = r & 63;
        int pf = r >> 6;
        int f  = pf & 7;
        int pk = pf >> 3;
        int k  = pk % INP_KSTEPS;
        int p  = pk / INP_KSTEPS;
        int row = p*128 + f*16 + (l & 15);
        int col = k*32 + (l >> 4)*8;
        const float* s = inw + (size_t)e2*2*D_INNER*D_MODEL + (size_t)row*D_MODEL + col;
        __hip_bfloat16 o8[8];
        #pragma unroll
        for (int e = 0; e < 8; e++) o8[e] = __float2bfloat16(s[e]);
        *(uint4*)(inwp + (size_t)e2*INP_LAYER + (size_t)r*8) = *(uint4*)o8;
    } else if (i < N3+N4+NPI+NPO) {
        int j = i - N3 - N4 - NPI;
        const int PER_LAYER = OUTP_LAYER/8;
        int e2 = j / PER_LAYER;
        int r  = j % PER_LAYER;
        int l  = r & 63;
        int pf = r >> 6;
        int f  = pf & 3;
        int pk = pf >> 2;
        int k  = pk % OUTP_KSTEPS;
        int p  = pk / OUTP_KSTEPS;
        int row = p*64 + f*16 + (l & 15);
        int col = k*32 + (l >> 4)*8;
        const float* s = outw + (size_t)e2*D_MODEL*D_INNER + (size_t)row*D_INNER + col;
        __hip_bfloat16 o8[8];
        #pragma unroll
        for (int e = 0; e < 8; e++) o8[e] = __float2bfloat16(s[e]);
        *(uint4*)(outwp + (size_t)e2*OUTP_LAYER + (size_t)r*8) = *(uint4*)o8;
    }
}

// ---------------------------------------------------------------- stats (RevIN)
__global__ __launch_bounds__(256) void stats_kernel(const float* __restrict__ x,
                                                    float* __restrict__ mean,
                                                    float* __restrict__ stdv) {
    int bc = blockIdx.x;
    int b = bc / ENC_IN, c = bc % ENC_IN;
    __shared__ float tmp[4];
    float s = 0.f, sq = 0.f;
    for (int l = threadIdx.x; l < LSEQ; l += 256) {
        float v = x[((size_t)(b*LSEQ + l))*ENC_IN + c];
        s += v; sq += v*v;
    }
    s = block_sum(s, tmp);
    sq = block_sum(sq, tmp);
    if (threadIdx.x == 0) {
        float m = s / LSEQ;
        float var = sq / LSEQ - m*m;
        if (var < 0.f) var = 0.f;
        mean[bc] = m;
        stdv[bc] = sqrtf(var + EPSV);
    }
}

// ---------------------------------------------------------------- embedding
__global__ __launch_bounds__(256) void embed_kernel(const float* __restrict__ x,
                                                    const float* __restrict__ token_w,
                                                    const float* __restrict__ time_w,
                                                    const float* __restrict__ mean,
                                                    const float* __restrict__ stdv,
                                                    float* __restrict__ h) {
    int bl = blockIdx.x;
    int b = bl >> 9, l = bl & 511;
    __shared__ float sxc[ENC_IN*3];
    if (threadIdx.x < ENC_IN*3) {
        int c = threadIdx.x / 3, k = threadIdx.x % 3;
        int lk = (l + k - 1) & 511;
        float v = x[((size_t)(b*LSEQ + lk))*ENC_IN + c];
        sxc[threadIdx.x] = (v - mean[b*ENC_IN + c]) / stdv[b*ENC_IN + c];
    }
    __syncthreads();
    #pragma unroll
    for (int i = 0; i < 3; i++) {
        int d = threadIdx.x + i*256;
        float acc = 0.f;
        const float* w = token_w + (size_t)d*21;
        #pragma unroll
        for (int t = 0; t < 21; t++) acc += sxc[t] * w[t];
        int d2 = d & ~1;
        float div = __expf((float)d2 * (-9.210340371976184f / (float)D_MODEL));
        float ang = (float)l * div;
        float pe = (d & 1) ? cosf(ang) : sinf(ang);
        float tm = ((float)l / (float)LSEQ) * time_w[d];
        h[(size_t)bl*D_MODEL + d] = acc + pe + tm;
    }
}

// ---------------------------------------------------------------- rmsnorm -> bf16 (vectorized)
__global__ __launch_bounds__(256) void rmsnorm_bf16(const float* __restrict__ h,
                                                    const float* __restrict__ w,
                                                    __hip_bfloat16* __restrict__ xn) {
    size_t base = (size_t)blockIdx.x * D_MODEL;
    __shared__ float tmp[4];
    int tid = threadIdx.x;
    f32x4 v = {0.f,0.f,0.f,0.f};
    if (tid < 192) v = *(const f32x4*)(h + base + tid*4);
    float ss = v[0]*v[0] + v[1]*v[1] + v[2]*v[2] + v[3]*v[3];
    ss = block_sum(ss, tmp);
    float inv = rsqrtf(ss / (float)D_MODEL + EPSV);
    if (tid < 192) {
        f32x4 wv = *(const f32x4*)(w + tid*4);
        __hip_bfloat16 o4[4];
        #pragma unroll
        for (int j = 0; j < 4; j++) o4[j] = __float2bfloat16(v[j]*inv*wv[j]);
        *(uint2*)(xn + base + tid*4) = *(uint2*)o4;
    }
}

// ---------------------------------------------------------------- in_proj MFMA GEMM (BM=128 x BN=128, BK=32)
__global__ __launch_bounds__(256) void gemm_inproj(const __hip_bfloat16* __restrict__ A,
                                                   const __hip_bfloat16* __restrict__ Bp,
                                                   __hip_bfloat16* __restrict__ Cxs,
                                                   __hip_bfloat16* __restrict__ Cg) {
    __shared__ __align__(16) __hip_bfloat16 As[3][128*32];   // 24 KB
    const int K = D_MODEL;
    const int NK = K/32;                                     // 24
    int tid = threadIdx.x, lane = tid & 63, w = tid >> 6;
    int gx = gridDim.x;                                      // 24
    int nwg = gx * gridDim.y;                                // 768
    int orig = blockIdx.y*gx + blockIdx.x;
    int swz = (orig & 7)*(nwg >> 3) + (orig >> 3);
    int m0 = (swz / gx) * 128;
    int pn = (swz % gx);                                     // B panel index
    int wr = w >> 1, wc = w & 1;
    int kq = lane >> 4, rr = lane & 15;

    f32x4 acc[4][4];
    #pragma unroll
    for (int i = 0; i < 4; i++)
        #pragma unroll
        for (int j = 0; j < 4; j++) acc[i][j] = (f32x4){0.f,0.f,0.f,0.f};

    const char* Ab = (const char*)A;
    char* AsB = (char*)As;

    int c0 = tid, c1 = tid + 256;
    int r0 = c0 >> 2, q0 = (c0 & 3) ^ ((r0 >> 1) & 3);
    int r1 = c1 >> 2, q1 = (c1 & 3) ^ ((r1 >> 1) & 3);
    int sw = (kq ^ ((rr >> 1) & 3)) * 16;

    auto stageA = [&](int buf, int kt) {
        int k0 = kt*32;
        glds16(Ab + ((size_t)(m0+r0)*K + k0 + q0*8)*2, AsB + buf*8192 + c0*16);
        glds16(Ab + ((size_t)(m0+r1)*K + k0 + q1*8)*2, AsB + buf*8192 + c1*16);
    };
    const __hip_bfloat16* Bbase = Bp + ((size_t)pn*INP_KSTEPS*8 + wc*4)*512 + lane*8;

    bf16x8 bcur[4], bnxt[4];
    stageA(0, 0);
    stageA(1, 1);
    #pragma unroll
    for (int ni = 0; ni < 4; ni++) bcur[ni] = *(const bf16x8*)(Bbase + ni*512);

    for (int k = 0; k < NK; k++) {
        int cur = k % 3;
        __builtin_amdgcn_s_barrier();
        if (k + 2 < NK) stageA((k + 2) % 3, k + 2);
        if (k + 1 < NK) {
            const __hip_bfloat16* bp = Bbase + (size_t)(k + 1)*8*512;
            #pragma unroll
            for (int ni = 0; ni < 4; ni++) bnxt[ni] = *(const bf16x8*)(bp + ni*512);
        }
        if (k + 2 < NK) asm volatile("s_waitcnt vmcnt(12)" ::: "memory");
        else            asm volatile("s_waitcnt vmcnt(0)" ::: "memory");
        __builtin_amdgcn_s_barrier();
        bf16x8 af[4];
        #pragma unroll
        for (int mi = 0; mi < 4; mi++) af[mi] = *(const bf16x8*)(AsB + cur*8192 + (wr*64 + mi*16 + rr)*64 + sw);
        __builtin_amdgcn_s_setprio(1);
        #pragma unroll
        for (int mi = 0; mi < 4; mi++)
            #pragma unroll
            for (int ni = 0; ni < 4; ni++)
                acc[mi][ni] = __builtin_amdgcn_mfma_f32_16x16x32_bf16(af[mi], bcur[ni], acc[mi][ni], 0, 0, 0);
        __builtin_amdgcn_s_setprio(0);
        #pragma unroll
        for (int ni = 0; ni < 4; ni++) bcur[ni] = bnxt[ni];
    }

    int n0 = pn * 128;
    #pragma unroll
    for (int mi = 0; mi < 4; mi++) {
        #pragma unroll
        for (int ni = 0; ni < 4; ni++) {
            int row0 = m0 + wr*64 + mi*16;
            int col  = n0 + wc*64 + ni*16 + rr;
            if (col >= D_INNER) {
                __hip_bfloat16 g4[4];
                #pragma unroll
                for (int r = 0; r < 4; r++) {
                    float v = acc[mi][ni][r];
                    g4[r] = __float2bfloat16(v / (1.f + __expf(-v)));   // silu
                }
                int cd = col - D_INNER;
                *(uint2*)&Cg[((size_t)(row0 >> 4)*D_INNER + cd)*16 + kq*4] = *(uint2*)g4;
            } else {
                #pragma unroll
                for (int r = 0; r < 4; r++) {
                    int row = row0 + kq*4 + r;
                    Cxs[(size_t)row*D_INNER + col] = __float2bfloat16(acc[mi][ni][r]);
                }
            }
        }
    }
}

// ---------------------------------------------------------------- dtproj MFMA (K=64, fused split-K reduction of pout)
__global__ __launch_bounds__(256) void gemm_dtproj(const float* __restrict__ P,
                                                   const __hip_bfloat16* __restrict__ Bw,
                                                   const float* __restrict__ bias,
                                                   float* __restrict__ xdbl,
                                                   __hip_bfloat16* __restrict__ delta) {
    __shared__ __align__(16) __hip_bfloat16 As[128*64];
    __shared__ __align__(16) __hip_bfloat16 Bs[128*64];
    const int K = 64;
    int tid = threadIdx.x, lane = tid & 63, w = tid >> 6;
    int gx = gridDim.x;
    int nwg = gx * gridDim.y;
    int orig = blockIdx.y*gx + blockIdx.x;
    int swz = (orig & 7)*(nwg >> 3) + (orig >> 3);
    int m0 = (swz / gx) * 128, n0 = (swz % gx) * 128;
    int wr = w >> 1, wc = w & 1;
    int kq = lane >> 4, rr = lane & 15;

    f32x4 acc[4][4];
    #pragma unroll
    for (int i = 0; i < 4; i++)
        #pragma unroll
        for (int j = 0; j < 4; j++) acc[i][j] = (f32x4){0.f,0.f,0.f,0.f};

    const char* Bb = (const char*)Bw;
    char* AsB = (char*)As;
    char* BsB = (char*)Bs;

    #pragma unroll
    for (int c = 0; c < 4; c++) {
        int idx = c*256 + tid;
        int r = idx >> 3, q = idx & 7;
        int qs = q ^ (r & 7);
        glds16(Bb + ((size_t)(n0+r)*K + qs*8)*2, BsB + idx*16);
    }

    const size_t RX = (size_t)ROWS*XN;
    #pragma unroll
    for (int it = 0; it < 2; it++) {
        int idx = it*1024 + tid;
        if (idx < 128*10) {
            int row = idx / 10, ch = idx % 10;
            const float* p0 = P + (size_t)(m0+row)*XN + ch*8;
            f32x4 a0 = *(const f32x4*)(p0)      + *(const f32x4*)(p0+RX)
                     + *(const f32x4*)(p0+2*RX) + *(const f32x4*)(p0+3*RX);
            f32x4 a1 = *(const f32x4*)(p0+4)        + *(const f32x4*)(p0+RX+4)
                     + *(const f32x4*)(p0+2*RX+4)   + *(const f32x4*)(p0+3*RX+4);
            if (n0 == 0) {
                float* xd = xdbl + (size_t)(m0+row)*XN + ch*8;
                *(f32x4*)(xd)   = a0;
                *(f32x4*)(xd+4) = a1;
            }
            if (ch < 8) {
                bf16x8 hv;
                if (ch < 6) {
                    #pragma unroll
                    for (int j = 0; j < 4; j++) { hv[j] = (__bf16)a0[j]; hv[4+j] = (__bf16)a1[j]; }
                } else {
                    bf16x8 z = {}; hv = z;
                }
                *(bf16x8*)(AsB + row*128 + ((ch ^ (row & 7))*16)) = hv;
            }
        }
    }
    __syncthreads();

    #pragma unroll
    for (int kh = 0; kh < 2; kh++) {
        int ch = ((kh*4 + kq) ^ (rr & 7)) * 16;
        bf16x8 af[4], bfr[4];
        #pragma unroll
        for (int mi = 0; mi < 4; mi++) af[mi]  = *(const bf16x8*)(AsB + (wr*64 + mi*16 + rr)*128 + ch);
        #pragma unroll
        for (int ni = 0; ni < 4; ni++) bfr[ni] = *(const bf16x8*)(BsB + (wc*64 + ni*16 + rr)*128 + ch);
        #pragma unroll
        for (int mi = 0; mi < 4; mi++)
            #pragma unroll
            for (int ni = 0; ni < 4; ni++)
                acc[mi][ni] = __builtin_amdgcn_mfma_f32_16x16x32_bf16(af[mi], bfr[ni], acc[mi][ni], 0, 0, 0);
    }

    #pragma unroll
    for (int mi = 0; mi < 4; mi++) {
        #pragma unroll
        for (int ni = 0; ni < 4; ni++) {
            int row0 = m0 + wr*64 + mi*16;
            int col  = n0 + wc*64 + ni*16 + rr;
            __hip_bfloat16 d4[4];
            #pragma unroll
            for (int r = 0; r < 4; r++) {
                float v = acc[mi][ni][r] + bias[col];
                d4[r] = __float2bfloat16(softplusf(v));
            }
            *(uint2*)&delta[((size_t)(row0 >> 4)*D_INNER + col)*16 + kq*4] = *(uint2*)d4;
        }
    }
}

// ---------------------------------------------------------------- out_proj: h += ygate @ W^T (A-only 3-ring + reg-B)
__global__ __launch_bounds__(256) void gemm_outproj(const __hip_bfloat16* __restrict__ A,
                                                    const __hip_bfloat16* __restrict__ Bp,
                                                    float* __restrict__ C) {
    __shared__ __align__(16) __hip_bfloat16 As[3][128*32];   // 24 KB
    int tid = threadIdx.x, lane = tid & 63, w = tid >> 6;
    int gx = gridDim.x;                       // 12
    int nwg = gx * gridDim.y;                 // 384
    int orig = blockIdx.y*gx + blockIdx.x;
    int swz = (orig & 7)*(nwg >> 3) + (orig >> 3);
    int m0 = (swz / gx) * 128;
    int pn = (swz % gx);                      // B panel (64 cols)
    int wr = w >> 1, wc = w & 1;
    int kq = lane >> 4, rr = lane & 15;
    const int K = D_INNER;
    const int NK = K/32;                      // 48

    f32x4 acc[4][2];
    #pragma unroll
    for (int i = 0; i < 4; i++)
        #pragma unroll
        for (int j = 0; j < 2; j++) acc[i][j] = (f32x4){0.f,0.f,0.f,0.f};

    const char* Ab = (const char*)A;
    char* AsB = (char*)As;

    int cA0 = tid, cA1 = tid + 256;
    int rA0 = cA0 >> 2, qA0 = (cA0 & 3) ^ ((rA0 >> 1) & 3);
    int rA1 = cA1 >> 2, qA1 = (cA1 & 3) ^ ((rA1 >> 1) & 3);
    int sw = (kq ^ ((rr >> 1) & 3)) * 16;

    auto stageA = [&](int buf, int kt) {
        int k0 = kt*32;
        glds16(Ab + ((size_t)(m0+rA0)*K + k0 + qA0*8)*2, AsB + buf*8192 + cA0*16);
        glds16(Ab + ((size_t)(m0+rA1)*K + k0 + qA1*8)*2, AsB + buf*8192 + cA1*16);
    };
    const __hip_bfloat16* Bbase = Bp + ((size_t)pn*OUTP_KSTEPS*4 + wc*2)*512 + lane*8;

    bf16x8 bcur[2], bnxt[2];
    stageA(0, 0);
    stageA(1, 1);
    #pragma unroll
    for (int ni = 0; ni < 2; ni++) bcur[ni] = *(const bf16x8*)(Bbase + ni*512);

    for (int k = 0; k < NK; k++) {
        int cur = k % 3;
        __builtin_amdgcn_s_barrier();
        if (k + 2 < NK) stageA((k + 2) % 3, k + 2);
        if (k + 1 < NK) {
            const __hip_bfloat16* bp = Bbase + (size_t)(k + 1)*4*512;
            #pragma unroll
            for (int ni = 0; ni < 2; ni++) bnxt[ni] = *(const bf16x8*)(bp + ni*512);
        }
        if (k + 2 < NK)      asm volatile("s_waitcnt vmcnt(8)" ::: "memory");
        else if (k + 1 < NK) asm volatile("s_waitcnt vmcnt(4)" ::: "memory");
        else                 asm volatile("s_waitcnt vmcnt(0)" ::: "memory");
        __builtin_amdgcn_s_barrier();
        bf16x8 af[4];
        #pragma unroll
        for (int mi = 0; mi < 4; mi++) af[mi] = *(const bf16x8*)(AsB + cur*8192 + (wr*64 + mi*16 + rr)*64 + sw);
        __builtin_amdgcn_s_setprio(1);
        #pragma unroll
        for (int mi = 0; mi < 4; mi++)
            #pragma unroll
            for (int ni = 0; ni < 2; ni++)
                acc[mi][ni] = __builtin_amdgcn_mfma_f32_16x16x32_bf16(af[mi], bcur[ni], acc[mi][ni], 0, 0, 0);
        __builtin_amdgcn_s_setprio(0);
        #pragma unroll
        for (int ni = 0; ni < 2; ni++) bcur[ni] = bnxt[ni];
    }

    int n0 = pn * 64;
    #pragma unroll
    for (int mi = 0; mi < 4; mi++) {
        #pragma unroll
        for (int ni = 0; ni < 2; ni++) {
            #pragma unroll
            for (int r = 0; r < 4; r++) {
                int row = m0 + wr*64 + mi*16 + kq*4 + r;
                int col = n0 + wc*32 + ni*16 + rr;
                size_t o = (size_t)row*D_MODEL + col;
                C[o] = acc[mi][ni][r] + C[o];
            }
        }
    }
}

// ---------------------------------------------------------------- xproj MFMA: partials, split-K (3-buffer ring)
__global__ __launch_bounds__(256) void gemm_xproj(const __hip_bfloat16* __restrict__ A,
                                                  const __hip_bfloat16* __restrict__ W,
                                                  float* __restrict__ P) {
    __shared__ __align__(16) __hip_bfloat16 As[3][64*64];
    __shared__ __align__(16) __hip_bfloat16 Bs[3][96*64];
    int tid = threadIdx.x, lane = tid & 63, w = tid >> 6;
    int m0 = blockIdx.x * 64;
    int k0 = blockIdx.y * (D_INNER / KSPLIT);
    int kq = lane >> 4, rr = lane & 15;
    const int NK = (D_INNER/KSPLIT)/64;       // 6
    f32x4 acc[5];
    #pragma unroll
    for (int i = 0; i < 5; i++) acc[i] = (f32x4){0.f,0.f,0.f,0.f};
    const char* Ab = (const char*)A;
    const char* Wb = (const char*)W;
    char* AsB = (char*)As;
    char* BsB = (char*)Bs;

    auto stage = [&](int buf, int it) {
        int kk = k0 + it*64;
        #pragma unroll
        for (int cA = 0; cA < 2; cA++) {
            int idx = cA*256 + tid;
            int r = idx >> 3, q = (idx & 7) ^ (r & 7);
            glds16(Ab + ((size_t)(m0+r)*D_INNER + kk + q*8)*2, AsB + buf*8192 + idx*16);
        }
        #pragma unroll
        for (int cB = 0; cB < 3; cB++) {
            int idx = cB*256 + tid;
            int r = idx >> 3, q = (idx & 7) ^ (r & 7);
            int rs = r < XN ? r : XN-1;
            glds16(Wb + ((size_t)rs*D_INNER + kk + q*8)*2, BsB + buf*12288 + idx*16);
        }
    };

    stage(0, 0);
    stage(1, 1);

    for (int it = 0; it < NK; it++) {
        int cur = it % 3;
        __builtin_amdgcn_s_barrier();
        if (it + 2 < NK) stage((it + 2) % 3, it + 2);
        if (it + 2 < NK)      asm volatile("s_waitcnt vmcnt(10)" ::: "memory");
        else if (it + 1 < NK) asm volatile("s_waitcnt vmcnt(5)" ::: "memory");
        else                  asm volatile("s_waitcnt vmcnt(0)" ::: "memory");
        __builtin_amdgcn_s_barrier();
        #pragma unroll
        for (int kh = 0; kh < 2; kh++) {
            bf16x8 a = *(const bf16x8*)(AsB + cur*8192 + (w*16 + rr)*128 + (((kh*4 + kq) ^ (rr & 7)))*16);
            #pragma unroll
            for (int ni = 0; ni < 5; ni++) {
                bf16x8 b = *(const bf16x8*)(BsB + cur*12288 + (ni*16 + rr)*128 + (((kh*4 + kq) ^ (rr & 7)))*16);
                acc[ni] = __builtin_amdgcn_mfma_f32_16x16x32_bf16(a, b, acc[ni], 0, 0, 0);
            }
        }
    }
    float* Cp = P + (size_t)blockIdx.y * ROWS * XN;
    #pragma unroll
    for (int ni = 0; ni < 5; ni++)
        #pragma unroll
        for (int r = 0; r < 4; r++) {
            int row = m0 + w*16 + kq*4 + r;
            int col = ni*16 + rr;
            Cp[(size_t)row*XN + col] = acc[ni][r];
        }
}

// ---------------------------------------------------------------- depthwise causal conv + SiLU (bf16 in/out, x8 vec)
__global__ __launch_bounds__(256) void dwconv_silu(const __hip_bfloat16* __restrict__ xs,
                                                   const float* __restrict__ cw,
                                                   const float* __restrict__ cb,
                                                   __hip_bfloat16* __restrict__ u_bf) {
    int idx = blockIdx.x*256 + threadIdx.x;
    int dg = idx % (D_INNER/8);
    int t  = idx / (D_INNER/8);
    if (t >= ROWS) return;
    int d0 = dg*8;
    int l = t & 511, b = t >> 9;
    bf16x8 rows[K_CONV];
    #pragma unroll
    for (int k = 0; k < K_CONV; k++) {
        int ll = l - (K_CONV-1) + k;
        if (ll >= 0) rows[k] = *(const bf16x8*)(xs + ((size_t)(b*LSEQ + ll))*D_INNER + d0);
        else { bf16x8 z = {}; rows[k] = z; }
    }
    bf16x8 outv;
    #pragma unroll
    for (int j = 0; j < 8; j++) {
        int d = d0 + j;
        const float4 w4 = *(const float4*)(cw + d*K_CONV);
        float acc = cb[d]
                  + (float)rows[0][j]*w4.x + (float)rows[1][j]*w4.y
                  + (float)rows[2][j]*w4.z + (float)rows[3][j]*w4.w;
        float v = acc / (1.f + __expf(-acc));
        outv[j] = (__bf16)v;
    }
    *(bf16x8*)(u_bf + (size_t)t*D_INNER + d0) = outv;
}

// ---------------------------------------------------------------- selective scan, ILP-2 (each thread: d and d+768)
__global__ __launch_bounds__(256) void scan_p1(const __hip_bfloat16* __restrict__ u,
                                               const __hip_bfloat16* __restrict__ delta_blk,
                                               const float* __restrict__ xdbl,
                                               const float* __restrict__ A_log,
                                               float* __restrict__ xfin,
                                               float* __restrict__ sumdlt) {
    int dd = blockIdx.x*256 + threadIdx.x;       // 0..DHALF-1
    int c = blockIdx.y, b = blockIdx.z;
    int l0 = c*CL;
    int dA = dd, dB = dd + DHALF;
    const float* alA = A_log + dA*N_STATE;
    const float* alB = A_log + dB*N_STATE;
    bool fast = true;
    #pragma unroll
    for (int n = 0; n < N_STATE; n++) {
        fast = fast && (fabsf(__expf(alA[n]) - (float)(n+1)) < 1e-3f)
                    && (fabsf(__expf(alB[n]) - (float)(n+1)) < 1e-3f);
    }
    float xsA[N_STATE], xsB[N_STATE];
    #pragma unroll
    for (int n = 0; n < N_STATE; n++) { xsA[n] = 0.f; xsB[n] = 0.f; }
    const __hip_bfloat16* puA = u + (size_t)(b*LSEQ + l0)*D_INNER + dA;
    const __hip_bfloat16* puB = u + (size_t)(b*LSEQ + l0)*D_INNER + dB;
    const float* pB = xdbl + (size_t)(b*LSEQ + l0)*XN + DT_RANK;
    float sdA = 0.f, sdB = 0.f;
    if (fast) {
        #pragma unroll
        for (int tt = 0; tt < 2; tt++) {
            size_t tbase = (size_t)(b*NTILE + (l0>>4) + tt)*D_INNER;
            const __hip_bfloat16* dbA = delta_blk + (tbase + dA)*16;
            const __hip_bfloat16* dbB = delta_blk + (tbase + dB)*16;
            bf16x8 dA0 = *(const bf16x8*)dbA, dA1 = *(const bf16x8*)(dbA + 8);
            bf16x8 dB0 = *(const bf16x8*)dbB, dB1 = *(const bf16x8*)(dbB + 8);
            #pragma unroll
            for (int i = 0; i < 16; i++) {
                float dltA = (float)(i < 8 ? dA0[i] : dA1[i-8]);
                float dltB = (float)(i < 8 ? dB0[i] : dB1[i-8]);
                float uuA = __bfloat162float(*puA); puA += D_INNER;
                float uuB = __bfloat162float(*puB); puB += D_INNER;
                float duA = dltA*uuA, duB = dltB*uuB;
                sdA += dltA; sdB += dltB;
                float e1A = fexp2(-dltA*LOG2E);
                float e1B = fexp2(-dltB*LOG2E);
                float eA = e1A, eB = e1B;
                xsA[0] = eA*xsA[0] + duA*pB[0];
                xsB[0] = eB*xsB[0] + duB*pB[0];
                #pragma unroll
                for (int n = 1; n < N_STATE; n++) {
                    eA *= e1A; eB *= e1B;
                    xsA[n] = eA*xsA[n] + duA*pB[n];
                    xsB[n] = eB*xsB[n] + duB*pB[n];
                }
                pB += XN;
            }
        }
    } else {
        #pragma unroll
        for (int tt = 0; tt < 2; tt++) {
            size_t tbase = (size_t)(b*NTILE + (l0>>4) + tt)*D_INNER;
            const __hip_bfloat16* dbA = delta_blk + (tbase + dA)*16;
            const __hip_bfloat16* dbB = delta_blk + (tbase + dB)*16;
            bf16x8 dA0 = *(const bf16x8*)dbA, dA1 = *(const bf16x8*)(dbA + 8);
            bf16x8 dB0 = *(const bf16x8*)dbB, dB1 = *(const bf16x8*)(dbB + 8);
            #pragma unroll
            for (int i = 0; i < 16; i++) {
                float dltA = (float)(i < 8 ? dA0[i] : dA1[i-8]);
                float dltB = (float)(i < 8 ? dB0[i] : dB1[i-8]);
                float uuA = __bfloat162float(*puA); puA += D_INNER;
                float uuB = __bfloat162float(*puB); puB += D_INNER;
                float duA = dltA*uuA, duB = dltB*uuB;
                sdA += dltA; sdB += dltB;
                #pragma unroll
                for (int n = 0; n < N_STATE; n++) {
                    float A2a = -__expf(alA[n]) * LOG2E;
                    float A2b = -__expf(alB[n]) * LOG2E;
                    xsA[n] = fexp2(dltA*A2a)*xsA[n] + duA*pB[n];
                    xsB[n] = fexp2(dltB*A2b)*xsB[n] + duB*pB[n];
                }
                pB += XN;
            }
        }
    }
    float* pxA = xfin + (size_t)((b*NC + c)*N_STATE)*D_INNER + dA;
    float* pxB = xfin + (size_t)((b*NC + c)*N_STATE)*D_INNER + dB;
    #pragma unroll
    for (int n = 0; n < N_STATE; n++) { pxA[n*D_INNER] = xsA[n]; pxB[n*D_INNER] = xsB[n]; }
    sumdlt[(size_t)(b*NC + c)*D_INNER + dA] = sdA;
    sumdlt[(size_t)(b*NC + c)*D_INNER + dB] = sdB;
}

__global__ __launch_bounds__(256) void scan_p2(float* __restrict__ xfin,
                                               const float* __restrict__ sumdlt,
                                               const float* __restrict__ A_log) {
    int idx = blockIdx.x*256 + threadIdx.x;
    int d = idx % D_INNER;
    int r = idx / D_INNER;
    int n = r & 15;
    int b = r >> 4;
    float A2 = -__expf(A_log[d*N_STATE + n]) * LOG2E;
    float cr = 0.f;
    for (int c = 1; c < NC; c++) {
        size_t jp = (size_t)(b*NC + c - 1);
        float xf = xfin[(jp*N_STATE + n)*D_INNER + d];
        float s  = sumdlt[jp*D_INNER + d];
        cr = fexp2(A2 * s) * cr + xf;
        xfin[(jp*N_STATE + n)*D_INNER + d] = cr;
    }
}

__global__ __launch_bounds__(256) void scan_p3(const __hip_bfloat16* __restrict__ u,
                                               const __hip_bfloat16* __restrict__ delta_blk,
                                               const __hip_bfloat16* __restrict__ gres,
                                               const float* __restrict__ xdbl,
                                               const float* __restrict__ A_log,
                                               const float* __restrict__ Dp,
                                               const float* __restrict__ carry,
                                               __hip_bfloat16* __restrict__ ygate) {
    int dd = blockIdx.x*256 + threadIdx.x;       // 0..DHALF-1
    int c = blockIdx.y, b = blockIdx.z;
    int l0 = c*CL;
    int dA = dd, dB = dd + DHALF;
    const float* alA = A_log + dA*N_STATE;
    const float* alB = A_log + dB*N_STATE;
    bool fast = true;
    #pragma unroll
    for (int n = 0; n < N_STATE; n++) {
        fast = fast && (fabsf(__expf(alA[n]) - (float)(n+1)) < 1e-3f)
                    && (fabsf(__expf(alB[n]) - (float)(n+1)) < 1e-3f);
    }
    float xsA[N_STATE], xsB[N_STATE];
    if (c == 0) {
        #pragma unroll
        for (int n = 0; n < N_STATE; n++) { xsA[n] = 0.f; xsB[n] = 0.f; }
    } else {
        const float* pcA = carry + (size_t)((b*NC + c - 1)*N_STATE)*D_INNER + dA;
        const float* pcB = carry + (size_t)((b*NC + c - 1)*N_STATE)*D_INNER + dB;
        #pragma unroll
        for (int n = 0; n < N_STATE; n++) { xsA[n] = pcA[n*D_INNER]; xsB[n] = pcB[n*D_INNER]; }
    }
    float DvA = Dp[dA], DvB = Dp[dB];
    const __hip_bfloat16* puA = u + (size_t)(b*LSEQ + l0)*D_INNER + dA;
    const __hip_bfloat16* puB = u + (size_t)(b*LSEQ + l0)*D_INNER + dB;
    const float* pB = xdbl + (size_t)(b*LSEQ + l0)*XN + DT_RANK;
    __hip_bfloat16* pyA = ygate + (size_t)(b*LSEQ + l0)*D_INNER + dA;
    __hip_bfloat16* pyB = ygate + (size_t)(b*LSEQ + l0)*D_INNER + dB;
    if (fast) {
        #pragma unroll
        for (int tt = 0; tt < 2; tt++) {
            size_t tbase = (size_t)(b*NTILE + (l0>>4) + tt)*D_INNER;
            const __hip_bfloat16* dbA = delta_blk + (tbase + dA)*16;
            const __hip_bfloat16* dbB = delta_blk + (tbase + dB)*16;
            bf16x8 dA0 = *(const bf16x8*)dbA, dA1 = *(const bf16x8*)(dbA + 8);
            bf16x8 dB0 = *(const bf16x8*)dbB, dB1 = *(const bf16x8*)(dbB + 8);
            const __hip_bfloat16* gbA = gres + (tbase + dA)*16;
            const __hip_bfloat16* gbB = gres + (tbase + dB)*16;
            bf16x8 gA0 = *(const bf16x8*)gbA, gA1 = *(const bf16x8*)(gbA + 8);
            bf16x8 gB0 = *(const bf16x8*)gbB, gB1 = *(const bf16x8*)(gbB + 8);
            #pragma unroll
            for (int i = 0; i < 16; i++) {
                float dltA = (float)(i < 8 ? dA0[i] : dA1[i-8]);
                float dltB = (float)(i < 8 ? dB0[i] : dB1[i-8]);
                float grA  = (float)(i < 8 ? gA0[i] : gA1[i-8]);
                float grB  = (float)(i < 8 ? gB0[i] : gB1[i-8]);
                float uuA = __bfloat162float(*puA); puA += D_INNER;
                float uuB = __bfloat162float(*puB); puB += D_INNER;
                float duA = dltA*uuA, duB = dltB*uuB;
                float e1A = fexp2(-dltA*LOG2E);
                float e1B = fexp2(-dltB*LOG2E);
                float eA = e1A, eB = e1B;
                float accA, accB;
                xsA[0] = eA*xsA[0] + duA*pB[0];
                xsB[0] = eB*xsB[0] + duB*pB[0];
                accA = xsA[0]*pB[N_STATE + 0];
                accB = xsB[0]*pB[N_STATE + 0];
                #pragma unroll
                for (int n = 1; n < N_STATE; n++) {
                    eA *= e1A; eB *= e1B;
                    xsA[n] = eA*xsA[n] + duA*pB[n];
                    xsB[n] = eB*xsB[n] + duB*pB[n];
                    accA += xsA[n]*pB[N_STATE + n];
                    accB += xsB[n]*pB[N_STATE + n];
                }
                pB += XN;
                float yA = accA + uuA*DvA;
                float yB = accB + uuB*DvB;
                *pyA = __float2bfloat16(yA * grA); pyA += D_INNER;
                *pyB = __float2bfloat16(yB * grB); pyB += D_INNER;
            }
        }
    } else {
        #pragma unroll
        for (int tt = 0; tt < 2; tt++) {
            size_t tbase = (size_t)(b*NTILE + (l0>>4) + tt)*D_INNER;
            const __hip_bfloat16* dbA = delta_blk + (tbase + dA)*16;
            const __hip_bfloat16* dbB = delta_blk + (tbase + dB)*16;
            bf16x8 dA0 = *(const bf16x8*)dbA, dA1 = *(const bf16x8*)(dbA + 8);
            bf16x8 dB0 = *(const bf16x8*)dbB, dB1 = *(const bf16x8*)(dbB + 8);
            const __hip_bfloat16* gbA = gres + (tbase + dA)*16;
            const __hip_bfloat16* gbB = gres + (tbase + dB)*16;
            bf16x8 gA0 = *(const bf16x8*)gbA, gA1 = *(const bf16x8*)(gbA + 8);
            bf16x8 gB0 = *(const bf16x8*)gbB, gB1 = *(const bf16x8*)(gbB + 8);
            #pragma unroll
            for (int i = 0; i < 16; i++) {
                float dltA = (float)(i < 8 ? dA0[i] : dA1[i-8]);
                float dltB = (float)(i < 8 ? dB0[i] : dB1[i-8]);
                float grA  = (float)(i < 8 ? gA0[i] : gA1[i-8]);
                float grB  = (float)(i < 8 ? gB0[i] : gB1[i-8]);
                float uuA = __bfloat162float(*puA); puA += D_INNER;
                float uuB = __bfloat162float(*puB); puB += D_INNER;
                float duA = dltA*uuA, duB = dltB*uuB;
                float accA = 0.f, accB = 0.f;
                #pragma unroll
                for (int n = 0; n < N_STATE; n++) {
                    float A2a = -__expf(alA[n]) * LOG2E;
                    float A2b = -__expf(alB[n]) * LOG2E;
                    xsA[n] = fexp2(dltA*A2a)*xsA[n] + duA*pB[n];
                    xsB[n] = fexp2(dltB*A2b)*xsB[n] + duB*pB[n];
                    accA += xsA[n]*pB[N_STATE + n];
                    accB += xsB[n]*pB[N_STATE + n];
                }
                pB += XN;
                float yA = accA + uuA*DvA;
                float yB = accB + uuB*DvB;
                *pyA = __float2bfloat16(yA * grA); pyA += D_INNER;
                *pyB = __float2bfloat16(yB * grB); pyB += D_INNER;
            }
        }
    }
}

// ---------------------------------------------------------------- final norm + head + de-norm
__global__ __launch_bounds__(256) void final_kernel(const float* __restrict__ h,
                                                    const float* __restrict__ fnw,
                                                    const float* __restrict__ out_w,
                                                    const float* __restrict__ mean,
                                                    const float* __restrict__ stdv,
                                                    float* __restrict__ out) {
    int bid = blockIdx.x;
    int b = bid / PRED_LEN, lo = bid % PRED_LEN;
    int l = LSEQ - PRED_LEN + lo;
    const float* row = h + ((size_t)(b*LSEQ + l))*D_MODEL;
    __shared__ float tmp[4];
    float ss = 0.f;
    for (int k = threadIdx.x; k < D_MODEL; k += 256) { float v = row[k]; ss += v*v; }
    ss = block_sum(ss, tmp);
    float inv = rsqrtf(ss / (float)D_MODEL + EPSV);
    float acc[C_OUT] = {};
    for (int k = threadIdx.x; k < D_MODEL; k += 256) {
        float hn = row[k]*fnw[k];
        #pragma unroll
        for (int c = 0; c < C_OUT; c++) acc[c] += hn*out_w[c*D_MODEL + k];
    }
    #pragma unroll
    for (int c = 0; c < C_OUT; c++) {
        float s = block_sum(acc[c], tmp);
        if (threadIdx.x == 0)
            out[((size_t)(b*PRED_LEN + lo))*C_OUT + c] = s*inv*stdv[b*ENC_IN + c] + mean[b*ENC_IN + c];
    }
}

// ---------------------------------------------------------------- launch
extern "C" void kernel_launch(void* const* d_in, const int* in_sizes, int n_in,
                              void* d_out, int out_size, void* d_ws, size_t ws_size,
                              hipStream_t stream) {
    const float* x        = (const float*)d_in[0];
    const float* token_w  = (const float*)d_in[1];
    const float* time_w   = (const float*)d_in[2];
    const float* norm_w   = (const float*)d_in[3];
    const float* in_w     = (const float*)d_in[4];
    const float* conv_w   = (const float*)d_in[5];
    const float* conv_b   = (const float*)d_in[6];
    const float* xproj_w  = (const float*)d_in[7];
    const float* dtproj_w = (const float*)d_in[8];
    const float* dtproj_b = (const float*)d_in[9];
    const float* A_log    = (const float*)d_in[10];
    const float* Dp       = (const float*)d_in[11];
    const float* outproj_w= (const float*)d_in[12];
    const float* final_nw = (const float*)d_in[13];
    const float* out_w    = (const float*)d_in[14];
    float* out = (float*)d_out;

    float* ws   = (float*)d_ws;
    float* mean = ws;
    float* stdv = ws + 64;
    float* h    = ws + 128;                            // ROWS*D_MODEL
    float* xdbl = h    + (size_t)ROWS*D_MODEL;         // ROWS*80 f32
    float* sumd = xdbl + (size_t)ROWS*XN;              // BSZ*NC*D_INNER
    float* xfin = sumd + (size_t)BSZ*NC*D_INNER;       // BSZ*NC*N_STATE*D_INNER
    float* pout = xfin + (size_t)BSZ*NC*D_INNER*N_STATE; // KSPLIT*ROWS*XN partials
    float* fend = pout + (size_t)KSPLIT*ROWS*XN;
    __hip_bfloat16* xn_bf  = (__hip_bfloat16*)fend;
    __hip_bfloat16* xs_bf  = xn_bf + (size_t)ROWS*D_MODEL;
    __hip_bfloat16* u_bf   = xs_bf + (size_t)ROWS*D_INNER;
    __hip_bfloat16* gres   = u_bf  + (size_t)ROWS*D_INNER;
    __hip_bfloat16* ygate  = gres  + (size_t)ROWS*D_INNER;
    __hip_bfloat16* delta  = ygate + (size_t)ROWS*D_INNER;
    __hip_bfloat16* inwp   = delta + (size_t)ROWS*D_INNER;           // packed in_w
    __hip_bfloat16* outwp  = inwp  + (size_t)E_LAYERS*INP_LAYER;     // packed out_w
    __hip_bfloat16* xpw_bf = outwp + (size_t)E_LAYERS*OUTP_LAYER;
    __hip_bfloat16* dtw_bf = xpw_bf + (size_t)E_LAYERS*XN*D_INNER;

    {
        const int NT = E_LAYERS*XN*D_INNER + E_LAYERS*D_INNER*64
                     + E_LAYERS*INP_LAYER/8 + E_LAYERS*OUTP_LAYER/8;
        prep_all<<<(NT+255)/256, 256, 0, stream>>>(xproj_w, dtproj_w, in_w, outproj_w,
                                                   xpw_bf, dtw_bf, inwp, outwp);
    }

    stats_kernel<<<BSZ*ENC_IN, 256, 0, stream>>>(x, mean, stdv);
    embed_kernel<<<ROWS, 256, 0, stream>>>(x, token_w, time_w, mean, stdv, h);

    for (int e = 0; e < E_LAYERS; e++) {
        rmsnorm_bf16<<<ROWS, 256, 0, stream>>>(h, norm_w + e*D_MODEL, xn_bf);
        gemm_inproj<<<dim3(2*D_INNER/128, ROWS/128), 256, 0, stream>>>(
            xn_bf, inwp + (size_t)e*INP_LAYER, xs_bf, gres);
        dwconv_silu<<<(ROWS*(D_INNER/8) + 255)/256, 256, 0, stream>>>(
            xs_bf, conv_w + (size_t)e*D_INNER*K_CONV, conv_b + e*D_INNER, u_bf);
        gemm_xproj<<<dim3(ROWS/64, KSPLIT), 256, 0, stream>>>(
            u_bf, xpw_bf + (size_t)e*XN*D_INNER, pout);
        gemm_dtproj<<<dim3(D_INNER/128, ROWS/128), 256, 0, stream>>>(
            pout, dtw_bf + (size_t)e*D_INNER*64, dtproj_b + e*D_INNER, xdbl, delta);
        const float* Alog_e = A_log + (size_t)e*D_INNER*N_STATE;
        scan_p1<<<dim3(DHALF/256, NC, BSZ), 256, 0, stream>>>(
            u_bf, delta, xdbl, Alog_e, xfin, sumd);
        scan_p2<<<(BSZ*D_INNER*N_STATE)/256, 256, 0, stream>>>(
            xfin, sumd, Alog_e);
        scan_p3<<<dim3(DHALF/256, NC, BSZ), 256, 0, stream>>>(
            u_bf, delta, gres, xdbl, Alog_e, Dp + (size_t)e*D_INNER, xfin, ygate);
        gemm_outproj<<<dim3(D_MODEL/64, ROWS/128), 256, 0, stream>>>(
            ygate, outwp + (size_t)e*OUTP_LAYER, h);
    }

    final_kernel<<<BSZ*PRED_LEN, 256, 0, stream>>>(h, final_nw, out_w, mean, stdv, out);
}

// Round 18
// 376.640 us; speedup vs baseline: 1.0738x; 1.0738x over previous
//
#include <hip/hip_runtime.h>
#include <hip/hip_bf16.h>
#include <math.h>

// Problem constants
#define BSZ 8
#define LSEQ 512
#define ENC_IN 7
#define D_MODEL 768
#define D_INNER 1536
#define DT_RANK 48
#define N_STATE 16
#define K_CONV 4
#define E_LAYERS 2
#define C_OUT 7
#define PRED_LEN 96
#define EPSV 1e-5f
#define XN 80
#define KSPLIT 4

#define ROWS (BSZ*LSEQ)            // 4096
#define NC 16                      // scan chunks
#define CL (LSEQ/NC)               // 32 steps per chunk
#define NTILE (LSEQ/16)            // 32 16-step tiles per batch
#define LOG2E 1.44269504088896f
// packed in_w geometry: 24 panels x 24 ksteps x 8 frags x 64 lanes x 8 elems
#define INP_PANELS (2*D_INNER/128)     // 24
#define INP_KSTEPS (D_MODEL/32)        // 24
#define INP_LAYER  (INP_PANELS*INP_KSTEPS*8*64*8)   // 2359296
// packed out_w geometry: 12 panels x 48 ksteps x 4 frags x 64 lanes x 8 elems
#define OUTP_PANELS (D_MODEL/64)       // 12
#define OUTP_KSTEPS (D_INNER/32)       // 48
#define OUTP_LAYER  (OUTP_PANELS*OUTP_KSTEPS*4*64*8)  // 1179648

typedef __bf16 bf16x8 __attribute__((ext_vector_type(8)));
typedef float  f32x4  __attribute__((ext_vector_type(4)));

__device__ __forceinline__ float fexp2(float x) {
    float r;
    asm("v_exp_f32 %0, %1" : "=v"(r) : "v"(x));
    return r;
}
__device__ __forceinline__ float softplusf(float v) {
    return fmaxf(v, 0.f) + log1pf(__expf(-fabsf(v)));
}
__device__ __forceinline__ void glds16(const char* g, char* l) {
    __builtin_amdgcn_global_load_lds((const __attribute__((address_space(1))) unsigned int*)g,
                                     (__attribute__((address_space(3))) unsigned int*)l, 16, 0, 0);
}

// ---------------------------------------------------------------- utilities
__device__ __forceinline__ float block_sum(float v, float* tmp) {
    #pragma unroll
    for (int off = 32; off > 0; off >>= 1) v += __shfl_down(v, off);
    int lane = threadIdx.x & 63, wid = threadIdx.x >> 6;
    __syncthreads();
    if (lane == 0) tmp[wid] = v;
    __syncthreads();
    return tmp[0] + tmp[1] + tmp[2] + tmp[3];
}

// ---------------------------------------------------------------- single fused prologue: cvt xpw/dtw + pack inw/outw
__global__ __launch_bounds__(256) void prep_all(const float* __restrict__ xpw,
                                                const float* __restrict__ dtw,
                                                const float* __restrict__ inw,
                                                const float* __restrict__ outw,
                                                __hip_bfloat16* __restrict__ xpw_bf,
                                                __hip_bfloat16* __restrict__ dtw_bf,
                                                __hip_bfloat16* __restrict__ inwp,
                                                __hip_bfloat16* __restrict__ outwp) {
    const int N3 = E_LAYERS*XN*D_INNER;
    const int N4 = E_LAYERS*D_INNER*64;
    const int NPI = E_LAYERS*INP_LAYER/8;
    const int NPO = E_LAYERS*OUTP_LAYER/8;
    int i = blockIdx.x*256 + threadIdx.x;
    if (i < N3) {
        xpw_bf[i] = __float2bfloat16(xpw[i]);
    } else if (i < N3+N4) {
        int j = i - N3;
        int r = j >> 6, c = j & 63;
        dtw_bf[j] = __float2bfloat16(c < DT_RANK ? dtw[r*DT_RANK + c] : 0.f);
    } else if (i < N3+N4+NPI) {
        int j = i - N3 - N4;
        const int PER_LAYER = INP_LAYER/8;
        int e2 = j / PER_LAYER;
        int r  = j % PER_LAYER;
        int l  = r & 63;
        int pf = r >> 6;
        int f  = pf & 7;
        int pk = pf >> 3;
        int k  = pk % INP_KSTEPS;
        int p  = pk / INP_KSTEPS;
        int row = p*128 + f*16 + (l & 15);
        int col = k*32 + (l >> 4)*8;
        const float* s = inw + (size_t)e2*2*D_INNER*D_MODEL + (size_t)row*D_MODEL + col;
        __hip_bfloat16 o8[8];
        #pragma unroll
        for (int e = 0; e < 8; e++) o8[e] = __float2bfloat16(s[e]);
        *(uint4*)(inwp + (size_t)e2*INP_LAYER + (size_t)r*8) = *(uint4*)o8;
    } else if (i < N3+N4+NPI+NPO) {
        int j = i - N3 - N4 - NPI;
        const int PER_LAYER = OUTP_LAYER/8;
        int e2 = j / PER_LAYER;
        int r  = j % PER_LAYER;
        int l  = r & 63;
        int pf = r >> 6;
        int f  = pf & 3;
        int pk = pf >> 2;
        int k  = pk % OUTP_KSTEPS;
        int p  = pk / OUTP_KSTEPS;
        int row = p*64 + f*16 + (l & 15);
        int col = k*32 + (l >> 4)*8;
        const float* s = outw + (size_t)e2*D_MODEL*D_INNER + (size_t)row*D_INNER + col;
        __hip_bfloat16 o8[8];
        #pragma unroll
        for (int e = 0; e < 8; e++) o8[e] = __float2bfloat16(s[e]);
        *(uint4*)(outwp + (size_t)e2*OUTP_LAYER + (size_t)r*8) = *(uint4*)o8;
    }
}

// ---------------------------------------------------------------- stats (RevIN)
__global__ __launch_bounds__(256) void stats_kernel(const float* __restrict__ x,
                                                    float* __restrict__ mean,
                                                    float* __restrict__ stdv) {
    int bc = blockIdx.x;
    int b = bc / ENC_IN, c = bc % ENC_IN;
    __shared__ float tmp[4];
    float s = 0.f, sq = 0.f;
    for (int l = threadIdx.x; l < LSEQ; l += 256) {
        float v = x[((size_t)(b*LSEQ + l))*ENC_IN + c];
        s += v; sq += v*v;
    }
    s = block_sum(s, tmp);
    sq = block_sum(sq, tmp);
    if (threadIdx.x == 0) {
        float m = s / LSEQ;
        float var = sq / LSEQ - m*m;
        if (var < 0.f) var = 0.f;
        mean[bc] = m;
        stdv[bc] = sqrtf(var + EPSV);
    }
}

// ---------------------------------------------------------------- embedding
__global__ __launch_bounds__(256) void embed_kernel(const float* __restrict__ x,
                                                    const float* __restrict__ token_w,
                                                    const float* __restrict__ time_w,
                                                    const float* __restrict__ mean,
                                                    const float* __restrict__ stdv,
                                                    float* __restrict__ h) {
    int bl = blockIdx.x;
    int b = bl >> 9, l = bl & 511;
    __shared__ float sxc[ENC_IN*3];
    if (threadIdx.x < ENC_IN*3) {
        int c = threadIdx.x / 3, k = threadIdx.x % 3;
        int lk = (l + k - 1) & 511;
        float v = x[((size_t)(b*LSEQ + lk))*ENC_IN + c];
        sxc[threadIdx.x] = (v - mean[b*ENC_IN + c]) / stdv[b*ENC_IN + c];
    }
    __syncthreads();
    #pragma unroll
    for (int i = 0; i < 3; i++) {
        int d = threadIdx.x + i*256;
        float acc = 0.f;
        const float* w = token_w + (size_t)d*21;
        #pragma unroll
        for (int t = 0; t < 21; t++) acc += sxc[t] * w[t];
        int d2 = d & ~1;
        float div = __expf((float)d2 * (-9.210340371976184f / (float)D_MODEL));
        float ang = (float)l * div;
        float pe = (d & 1) ? cosf(ang) : sinf(ang);
        float tm = ((float)l / (float)LSEQ) * time_w[d];
        h[(size_t)bl*D_MODEL + d] = acc + pe + tm;
    }
}

// ---------------------------------------------------------------- rmsnorm -> bf16 (vectorized)
__global__ __launch_bounds__(256) void rmsnorm_bf16(const float* __restrict__ h,
                                                    const float* __restrict__ w,
                                                    __hip_bfloat16* __restrict__ xn) {
    size_t base = (size_t)blockIdx.x * D_MODEL;
    __shared__ float tmp[4];
    int tid = threadIdx.x;
    f32x4 v = {0.f,0.f,0.f,0.f};
    if (tid < 192) v = *(const f32x4*)(h + base + tid*4);
    float ss = v[0]*v[0] + v[1]*v[1] + v[2]*v[2] + v[3]*v[3];
    ss = block_sum(ss, tmp);
    float inv = rsqrtf(ss / (float)D_MODEL + EPSV);
    if (tid < 192) {
        f32x4 wv = *(const f32x4*)(w + tid*4);
        __hip_bfloat16 o4[4];
        #pragma unroll
        for (int j = 0; j < 4; j++) o4[j] = __float2bfloat16(v[j]*inv*wv[j]);
        *(uint2*)(xn + base + tid*4) = *(uint2*)o4;
    }
}

// ---------------------------------------------------------------- in_proj MFMA GEMM (BM=128 x BN=128, BK=32)
__global__ __launch_bounds__(256) void gemm_inproj(const __hip_bfloat16* __restrict__ A,
                                                   const __hip_bfloat16* __restrict__ Bp,
                                                   __hip_bfloat16* __restrict__ Cxs,
                                                   __hip_bfloat16* __restrict__ Cg) {
    __shared__ __align__(16) __hip_bfloat16 As[3][128*32];   // 24 KB
    const int K = D_MODEL;
    const int NK = K/32;                                     // 24
    int tid = threadIdx.x, lane = tid & 63, w = tid >> 6;
    int gx = gridDim.x;                                      // 24
    int nwg = gx * gridDim.y;                                // 768
    int orig = blockIdx.y*gx + blockIdx.x;
    int swz = (orig & 7)*(nwg >> 3) + (orig >> 3);
    int m0 = (swz / gx) * 128;
    int pn = (swz % gx);                                     // B panel index
    int wr = w >> 1, wc = w & 1;
    int kq = lane >> 4, rr = lane & 15;

    f32x4 acc[4][4];
    #pragma unroll
    for (int i = 0; i < 4; i++)
        #pragma unroll
        for (int j = 0; j < 4; j++) acc[i][j] = (f32x4){0.f,0.f,0.f,0.f};

    const char* Ab = (const char*)A;
    char* AsB = (char*)As;

    int c0 = tid, c1 = tid + 256;
    int r0 = c0 >> 2, q0 = (c0 & 3) ^ ((r0 >> 1) & 3);
    int r1 = c1 >> 2, q1 = (c1 & 3) ^ ((r1 >> 1) & 3);
    int sw = (kq ^ ((rr >> 1) & 3)) * 16;

    auto stageA = [&](int buf, int kt) {
        int k0 = kt*32;
        glds16(Ab + ((size_t)(m0+r0)*K + k0 + q0*8)*2, AsB + buf*8192 + c0*16);
        glds16(Ab + ((size_t)(m0+r1)*K + k0 + q1*8)*2, AsB + buf*8192 + c1*16);
    };
    const __hip_bfloat16* Bbase = Bp + ((size_t)pn*INP_KSTEPS*8 + wc*4)*512 + lane*8;

    bf16x8 bcur[4], bnxt[4];
    stageA(0, 0);
    stageA(1, 1);
    #pragma unroll
    for (int ni = 0; ni < 4; ni++) bcur[ni] = *(const bf16x8*)(Bbase + ni*512);

    for (int k = 0; k < NK; k++) {
        int cur = k % 3;
        __builtin_amdgcn_s_barrier();
        if (k + 2 < NK) stageA((k + 2) % 3, k + 2);
        if (k + 1 < NK) {
            const __hip_bfloat16* bp = Bbase + (size_t)(k + 1)*8*512;
            #pragma unroll
            for (int ni = 0; ni < 4; ni++) bnxt[ni] = *(const bf16x8*)(bp + ni*512);
        }
        if (k + 2 < NK) asm volatile("s_waitcnt vmcnt(12)" ::: "memory");
        else            asm volatile("s_waitcnt vmcnt(0)" ::: "memory");
        __builtin_amdgcn_s_barrier();
        bf16x8 af[4];
        #pragma unroll
        for (int mi = 0; mi < 4; mi++) af[mi] = *(const bf16x8*)(AsB + cur*8192 + (wr*64 + mi*16 + rr)*64 + sw);
        __builtin_amdgcn_s_setprio(1);
        #pragma unroll
        for (int mi = 0; mi < 4; mi++)
            #pragma unroll
            for (int ni = 0; ni < 4; ni++)
                acc[mi][ni] = __builtin_amdgcn_mfma_f32_16x16x32_bf16(af[mi], bcur[ni], acc[mi][ni], 0, 0, 0);
        __builtin_amdgcn_s_setprio(0);
        #pragma unroll
        for (int ni = 0; ni < 4; ni++) bcur[ni] = bnxt[ni];
    }

    int n0 = pn * 128;
    #pragma unroll
    for (int mi = 0; mi < 4; mi++) {
        #pragma unroll
        for (int ni = 0; ni < 4; ni++) {
            int row0 = m0 + wr*64 + mi*16;
            int col  = n0 + wc*64 + ni*16 + rr;
            if (col >= D_INNER) {
                __hip_bfloat16 g4[4];
                #pragma unroll
                for (int r = 0; r < 4; r++) {
                    float v = acc[mi][ni][r];
                    g4[r] = __float2bfloat16(v / (1.f + __expf(-v)));   // silu
                }
                int cd = col - D_INNER;
                *(uint2*)&Cg[((size_t)(row0 >> 4)*D_INNER + cd)*16 + kq*4] = *(uint2*)g4;
            } else {
                #pragma unroll
                for (int r = 0; r < 4; r++) {
                    int row = row0 + kq*4 + r;
                    Cxs[(size_t)row*D_INNER + col] = __float2bfloat16(acc[mi][ni][r]);
                }
            }
        }
    }
}

// ---------------------------------------------------------------- dtproj MFMA (K=64, fused split-K reduction of pout)
__global__ __launch_bounds__(256) void gemm_dtproj(const float* __restrict__ P,
                                                   const __hip_bfloat16* __restrict__ Bw,
                                                   const float* __restrict__ bias,
                                                   float* __restrict__ xdbl,
                                                   __hip_bfloat16* __restrict__ delta) {
    __shared__ __align__(16) __hip_bfloat16 As[128*64];
    __shared__ __align__(16) __hip_bfloat16 Bs[128*64];
    const int K = 64;
    int tid = threadIdx.x, lane = tid & 63, w = tid >> 6;
    int gx = gridDim.x;
    int nwg = gx * gridDim.y;
    int orig = blockIdx.y*gx + blockIdx.x;
    int swz = (orig & 7)*(nwg >> 3) + (orig >> 3);
    int m0 = (swz / gx) * 128, n0 = (swz % gx) * 128;
    int wr = w >> 1, wc = w & 1;
    int kq = lane >> 4, rr = lane & 15;

    f32x4 acc[4][4];
    #pragma unroll
    for (int i = 0; i < 4; i++)
        #pragma unroll
        for (int j = 0; j < 4; j++) acc[i][j] = (f32x4){0.f,0.f,0.f,0.f};

    const char* Bb = (const char*)Bw;
    char* AsB = (char*)As;
    char* BsB = (char*)Bs;

    #pragma unroll
    for (int c = 0; c < 4; c++) {
        int idx = c*256 + tid;
        int r = idx >> 3, q = idx & 7;
        int qs = q ^ (r & 7);
        glds16(Bb + ((size_t)(n0+r)*K + qs*8)*2, BsB + idx*16);
    }

    const size_t RX = (size_t)ROWS*XN;
    #pragma unroll
    for (int it = 0; it < 2; it++) {
        int idx = it*1024 + tid;
        if (idx < 128*10) {
            int row = idx / 10, ch = idx % 10;
            const float* p0 = P + (size_t)(m0+row)*XN + ch*8;
            f32x4 a0 = *(const f32x4*)(p0)      + *(const f32x4*)(p0+RX)
                     + *(const f32x4*)(p0+2*RX) + *(const f32x4*)(p0+3*RX);
            f32x4 a1 = *(const f32x4*)(p0+4)        + *(const f32x4*)(p0+RX+4)
                     + *(const f32x4*)(p0+2*RX+4)   + *(const f32x4*)(p0+3*RX+4);
            if (n0 == 0) {
                float* xd = xdbl + (size_t)(m0+row)*XN + ch*8;
                *(f32x4*)(xd)   = a0;
                *(f32x4*)(xd+4) = a1;
            }
            if (ch < 8) {
                bf16x8 hv;
                if (ch < 6) {
                    #pragma unroll
                    for (int j = 0; j < 4; j++) { hv[j] = (__bf16)a0[j]; hv[4+j] = (__bf16)a1[j]; }
                } else {
                    bf16x8 z = {}; hv = z;
                }
                *(bf16x8*)(AsB + row*128 + ((ch ^ (row & 7))*16)) = hv;
            }
        }
    }
    __syncthreads();

    #pragma unroll
    for (int kh = 0; kh < 2; kh++) {
        int ch = ((kh*4 + kq) ^ (rr & 7)) * 16;
        bf16x8 af[4], bfr[4];
        #pragma unroll
        for (int mi = 0; mi < 4; mi++) af[mi]  = *(const bf16x8*)(AsB + (wr*64 + mi*16 + rr)*128 + ch);
        #pragma unroll
        for (int ni = 0; ni < 4; ni++) bfr[ni] = *(const bf16x8*)(BsB + (wc*64 + ni*16 + rr)*128 + ch);
        #pragma unroll
        for (int mi = 0; mi < 4; mi++)
            #pragma unroll
            for (int ni = 0; ni < 4; ni++)
                acc[mi][ni] = __builtin_amdgcn_mfma_f32_16x16x32_bf16(af[mi], bfr[ni], acc[mi][ni], 0, 0, 0);
    }

    #pragma unroll
    for (int mi = 0; mi < 4; mi++) {
        #pragma unroll
        for (int ni = 0; ni < 4; ni++) {
            int row0 = m0 + wr*64 + mi*16;
            int col  = n0 + wc*64 + ni*16 + rr;
            __hip_bfloat16 d4[4];
            #pragma unroll
            for (int r = 0; r < 4; r++) {
                float v = acc[mi][ni][r] + bias[col];
                d4[r] = __float2bfloat16(softplusf(v));
            }
            *(uint2*)&delta[((size_t)(row0 >> 4)*D_INNER + col)*16 + kq*4] = *(uint2*)d4;
        }
    }
}

// ---------------------------------------------------------------- out_proj: h += ygate @ W^T (A-only 3-ring + reg-B)
__global__ __launch_bounds__(256) void gemm_outproj(const __hip_bfloat16* __restrict__ A,
                                                    const __hip_bfloat16* __restrict__ Bp,
                                                    float* __restrict__ C) {
    __shared__ __align__(16) __hip_bfloat16 As[3][128*32];   // 24 KB
    int tid = threadIdx.x, lane = tid & 63, w = tid >> 6;
    int gx = gridDim.x;                       // 12
    int nwg = gx * gridDim.y;                 // 384
    int orig = blockIdx.y*gx + blockIdx.x;
    int swz = (orig & 7)*(nwg >> 3) + (orig >> 3);
    int m0 = (swz / gx) * 128;
    int pn = (swz % gx);                      // B panel (64 cols)
    int wr = w >> 1, wc = w & 1;
    int kq = lane >> 4, rr = lane & 15;
    const int K = D_INNER;
    const int NK = K/32;                      // 48

    f32x4 acc[4][2];
    #pragma unroll
    for (int i = 0; i < 4; i++)
        #pragma unroll
        for (int j = 0; j < 2; j++) acc[i][j] = (f32x4){0.f,0.f,0.f,0.f};

    const char* Ab = (const char*)A;
    char* AsB = (char*)As;

    int cA0 = tid, cA1 = tid + 256;
    int rA0 = cA0 >> 2, qA0 = (cA0 & 3) ^ ((rA0 >> 1) & 3);
    int rA1 = cA1 >> 2, qA1 = (cA1 & 3) ^ ((rA1 >> 1) & 3);
    int sw = (kq ^ ((rr >> 1) & 3)) * 16;

    auto stageA = [&](int buf, int kt) {
        int k0 = kt*32;
        glds16(Ab + ((size_t)(m0+rA0)*K + k0 + qA0*8)*2, AsB + buf*8192 + cA0*16);
        glds16(Ab + ((size_t)(m0+rA1)*K + k0 + qA1*8)*2, AsB + buf*8192 + cA1*16);
    };
    const __hip_bfloat16* Bbase = Bp + ((size_t)pn*OUTP_KSTEPS*4 + wc*2)*512 + lane*8;

    bf16x8 bcur[2], bnxt[2];
    stageA(0, 0);
    stageA(1, 1);
    #pragma unroll
    for (int ni = 0; ni < 2; ni++) bcur[ni] = *(const bf16x8*)(Bbase + ni*512);

    for (int k = 0; k < NK; k++) {
        int cur = k % 3;
        __builtin_amdgcn_s_barrier();
        if (k + 2 < NK) stageA((k + 2) % 3, k + 2);
        if (k + 1 < NK) {
            const __hip_bfloat16* bp = Bbase + (size_t)(k + 1)*4*512;
            #pragma unroll
            for (int ni = 0; ni < 2; ni++) bnxt[ni] = *(const bf16x8*)(bp + ni*512);
        }
        if (k + 2 < NK)      asm volatile("s_waitcnt vmcnt(8)" ::: "memory");
        else if (k + 1 < NK) asm volatile("s_waitcnt vmcnt(4)" ::: "memory");
        else                 asm volatile("s_waitcnt vmcnt(0)" ::: "memory");
        __builtin_amdgcn_s_barrier();
        bf16x8 af[4];
        #pragma unroll
        for (int mi = 0; mi < 4; mi++) af[mi] = *(const bf16x8*)(AsB + cur*8192 + (wr*64 + mi*16 + rr)*64 + sw);
        __builtin_amdgcn_s_setprio(1);
        #pragma unroll
        for (int mi = 0; mi < 4; mi++)
            #pragma unroll
            for (int ni = 0; ni < 2; ni++)
                acc[mi][ni] = __builtin_amdgcn_mfma_f32_16x16x32_bf16(af[mi], bcur[ni], acc[mi][ni], 0, 0, 0);
        __builtin_amdgcn_s_setprio(0);
        #pragma unroll
        for (int ni = 0; ni < 2; ni++) bcur[ni] = bnxt[ni];
    }

    int n0 = pn * 64;
    #pragma unroll
    for (int mi = 0; mi < 4; mi++) {
        #pragma unroll
        for (int ni = 0; ni < 2; ni++) {
            #pragma unroll
            for (int r = 0; r < 4; r++) {
                int row = m0 + wr*64 + mi*16 + kq*4 + r;
                int col = n0 + wc*32 + ni*16 + rr;
                size_t o = (size_t)row*D_MODEL + col;
                C[o] = acc[mi][ni][r] + C[o];
            }
        }
    }
}

// ---------------------------------------------------------------- xproj MFMA: partials, split-K (3-buffer ring)
__global__ __launch_bounds__(256) void gemm_xproj(const __hip_bfloat16* __restrict__ A,
                                                  const __hip_bfloat16* __restrict__ W,
                                                  float* __restrict__ P) {
    __shared__ __align__(16) __hip_bfloat16 As[3][64*64];
    __shared__ __align__(16) __hip_bfloat16 Bs[3][96*64];
    int tid = threadIdx.x, lane = tid & 63, w = tid >> 6;
    int m0 = blockIdx.x * 64;
    int k0 = blockIdx.y * (D_INNER / KSPLIT);
    int kq = lane >> 4, rr = lane & 15;
    const int NK = (D_INNER/KSPLIT)/64;       // 6
    f32x4 acc[5];
    #pragma unroll
    for (int i = 0; i < 5; i++) acc[i] = (f32x4){0.f,0.f,0.f,0.f};
    const char* Ab = (const char*)A;
    const char* Wb = (const char*)W;
    char* AsB = (char*)As;
    char* BsB = (char*)Bs;

    auto stage = [&](int buf, int it) {
        int kk = k0 + it*64;
        #pragma unroll
        for (int cA = 0; cA < 2; cA++) {
            int idx = cA*256 + tid;
            int r = idx >> 3, q = (idx & 7) ^ (r & 7);
            glds16(Ab + ((size_t)(m0+r)*D_INNER + kk + q*8)*2, AsB + buf*8192 + idx*16);
        }
        #pragma unroll
        for (int cB = 0; cB < 3; cB++) {
            int idx = cB*256 + tid;
            int r = idx >> 3, q = (idx & 7) ^ (r & 7);
            int rs = r < XN ? r : XN-1;
            glds16(Wb + ((size_t)rs*D_INNER + kk + q*8)*2, BsB + buf*12288 + idx*16);
        }
    };

    stage(0, 0);
    stage(1, 1);

    for (int it = 0; it < NK; it++) {
        int cur = it % 3;
        __builtin_amdgcn_s_barrier();
        if (it + 2 < NK) stage((it + 2) % 3, it + 2);
        if (it + 2 < NK)      asm volatile("s_waitcnt vmcnt(10)" ::: "memory");
        else if (it + 1 < NK) asm volatile("s_waitcnt vmcnt(5)" ::: "memory");
        else                  asm volatile("s_waitcnt vmcnt(0)" ::: "memory");
        __builtin_amdgcn_s_barrier();
        #pragma unroll
        for (int kh = 0; kh < 2; kh++) {
            bf16x8 a = *(const bf16x8*)(AsB + cur*8192 + (w*16 + rr)*128 + (((kh*4 + kq) ^ (rr & 7)))*16);
            #pragma unroll
            for (int ni = 0; ni < 5; ni++) {
                bf16x8 b = *(const bf16x8*)(BsB + cur*12288 + (ni*16 + rr)*128 + (((kh*4 + kq) ^ (rr & 7)))*16);
                acc[ni] = __builtin_amdgcn_mfma_f32_16x16x32_bf16(a, b, acc[ni], 0, 0, 0);
            }
        }
    }
    float* Cp = P + (size_t)blockIdx.y * ROWS * XN;
    #pragma unroll
    for (int ni = 0; ni < 5; ni++)
        #pragma unroll
        for (int r = 0; r < 4; r++) {
            int row = m0 + w*16 + kq*4 + r;
            int col = ni*16 + rr;
            Cp[(size_t)row*XN + col] = acc[ni][r];
        }
}

// ---------------------------------------------------------------- depthwise causal conv + SiLU (bf16 in/out, x8 vec)
__global__ __launch_bounds__(256) void dwconv_silu(const __hip_bfloat16* __restrict__ xs,
                                                   const float* __restrict__ cw,
                                                   const float* __restrict__ cb,
                                                   __hip_bfloat16* __restrict__ u_bf) {
    int idx = blockIdx.x*256 + threadIdx.x;
    int dg = idx % (D_INNER/8);
    int t  = idx / (D_INNER/8);
    if (t >= ROWS) return;
    int d0 = dg*8;
    int l = t & 511, b = t >> 9;
    bf16x8 rows[K_CONV];
    #pragma unroll
    for (int k = 0; k < K_CONV; k++) {
        int ll = l - (K_CONV-1) + k;
        if (ll >= 0) rows[k] = *(const bf16x8*)(xs + ((size_t)(b*LSEQ + ll))*D_INNER + d0);
        else { bf16x8 z = {}; rows[k] = z; }
    }
    bf16x8 outv;
    #pragma unroll
    for (int j = 0; j < 8; j++) {
        int d = d0 + j;
        const float4 w4 = *(const float4*)(cw + d*K_CONV);
        float acc = cb[d]
                  + (float)rows[0][j]*w4.x + (float)rows[1][j]*w4.y
                  + (float)rows[2][j]*w4.z + (float)rows[3][j]*w4.w;
        float v = acc / (1.f + __expf(-acc));
        outv[j] = (__bf16)v;
    }
    *(bf16x8*)(u_bf + (size_t)t*D_INNER + d0) = outv;
}

// ---------------------------------------------------------------- selective scan, 3-phase chunked (NC=16, CL=32)
__global__ __launch_bounds__(256) void scan_p1(const __hip_bfloat16* __restrict__ u,
                                               const __hip_bfloat16* __restrict__ delta_blk,
                                               const float* __restrict__ xdbl,
                                               const float* __restrict__ A_log,
                                               float* __restrict__ xfin,
                                               float* __restrict__ sumdlt) {
    int d = blockIdx.x*256 + threadIdx.x;
    int c = blockIdx.y, b = blockIdx.z;
    int l0 = c*CL;
    const float* al = A_log + d*N_STATE;
    bool fast = true;
    #pragma unroll
    for (int n = 0; n < N_STATE; n++)
        fast = fast && (fabsf(__expf(al[n]) - (float)(n+1)) < 1e-3f);
    float xs[N_STATE];
    #pragma unroll
    for (int n = 0; n < N_STATE; n++) xs[n] = 0.f;
    const __hip_bfloat16* pu = u + (size_t)(b*LSEQ + l0)*D_INNER + d;
    const float* pB = xdbl + (size_t)(b*LSEQ + l0)*XN + DT_RANK;
    float sd = 0.f;
    if (fast) {
        #pragma unroll
        for (int tt = 0; tt < 2; tt++) {
            const __hip_bfloat16* db = delta_blk + ((size_t)(b*NTILE + (l0>>4) + tt)*D_INNER + d)*16;
            bf16x8 d0 = *(const bf16x8*)db;
            bf16x8 d1 = *(const bf16x8*)(db + 8);
            #pragma unroll
            for (int i = 0; i < 16; i++) {
                float dlt = (float)(i < 8 ? d0[i] : d1[i-8]);
                float uu = __bfloat162float(*pu); pu += D_INNER;
                float du = dlt*uu;
                sd += dlt;
                float e1 = fexp2(-dlt*LOG2E);
                float e = e1;
                xs[0] = e*xs[0] + du*pB[0];
                #pragma unroll
                for (int n = 1; n < N_STATE; n++) {
                    e *= e1;
                    xs[n] = e*xs[n] + du*pB[n];
                }
                pB += XN;
            }
        }
    } else {
        #pragma unroll
        for (int tt = 0; tt < 2; tt++) {
            const __hip_bfloat16* db = delta_blk + ((size_t)(b*NTILE + (l0>>4) + tt)*D_INNER + d)*16;
            bf16x8 d0 = *(const bf16x8*)db;
            bf16x8 d1 = *(const bf16x8*)(db + 8);
            #pragma unroll
            for (int i = 0; i < 16; i++) {
                float dlt = (float)(i < 8 ? d0[i] : d1[i-8]);
                float uu = __bfloat162float(*pu); pu += D_INNER;
                float du = dlt*uu;
                sd += dlt;
                #pragma unroll
                for (int n = 0; n < N_STATE; n++) {
                    float A2n = -__expf(al[n]) * LOG2E;
                    xs[n] = fexp2(dlt*A2n)*xs[n] + du*pB[n];
                }
                pB += XN;
            }
        }
    }
    float* px = xfin + (size_t)((b*NC + c)*N_STATE)*D_INNER + d;
    #pragma unroll
    for (int n = 0; n < N_STATE; n++) px[n*D_INNER] = xs[n];
    sumdlt[(size_t)(b*NC + c)*D_INNER + d] = sd;
}

__global__ __launch_bounds__(256) void scan_p2(float* __restrict__ xfin,
                                               const float* __restrict__ sumdlt,
                                               const float* __restrict__ A_log) {
    int idx = blockIdx.x*256 + threadIdx.x;
    int d = idx % D_INNER;
    int r = idx / D_INNER;
    int n = r & 15;
    int b = r >> 4;
    float A2 = -__expf(A_log[d*N_STATE + n]) * LOG2E;
    float cr = 0.f;
    for (int c = 1; c < NC; c++) {
        size_t jp = (size_t)(b*NC + c - 1);
        float xf = xfin[(jp*N_STATE + n)*D_INNER + d];
        float s  = sumdlt[jp*D_INNER + d];
        cr = fexp2(A2 * s) * cr + xf;
        xfin[(jp*N_STATE + n)*D_INNER + d] = cr;
    }
}

__global__ __launch_bounds__(256) void scan_p3(const __hip_bfloat16* __restrict__ u,
                                               const __hip_bfloat16* __restrict__ delta_blk,
                                               const __hip_bfloat16* __restrict__ gres,
                                               const float* __restrict__ xdbl,
                                               const float* __restrict__ A_log,
                                               const float* __restrict__ Dp,
                                               const float* __restrict__ carry,
                                               __hip_bfloat16* __restrict__ ygate) {
    int d = blockIdx.x*256 + threadIdx.x;
    int c = blockIdx.y, b = blockIdx.z;
    int l0 = c*CL;
    const float* al = A_log + d*N_STATE;
    bool fast = true;
    #pragma unroll
    for (int n = 0; n < N_STATE; n++)
        fast = fast && (fabsf(__expf(al[n]) - (float)(n+1)) < 1e-3f);
    float xs[N_STATE];
    if (c == 0) {
        #pragma unroll
        for (int n = 0; n < N_STATE; n++) xs[n] = 0.f;
    } else {
        const float* pc = carry + (size_t)((b*NC + c - 1)*N_STATE)*D_INNER + d;
        #pragma unroll
        for (int n = 0; n < N_STATE; n++) xs[n] = pc[n*D_INNER];
    }
    float Dv = Dp[d];
    const __hip_bfloat16* pu = u + (size_t)(b*LSEQ + l0)*D_INNER + d;
    const float* pB = xdbl + (size_t)(b*LSEQ + l0)*XN + DT_RANK;
    __hip_bfloat16* py = ygate + (size_t)(b*LSEQ + l0)*D_INNER + d;
    if (fast) {
        #pragma unroll
        for (int tt = 0; tt < 2; tt++) {
            size_t tb = (size_t)(b*NTILE + (l0>>4) + tt)*D_INNER + d;
            const __hip_bfloat16* db = delta_blk + tb*16;
            bf16x8 d0 = *(const bf16x8*)db;
            bf16x8 d1 = *(const bf16x8*)(db + 8);
            const __hip_bfloat16* gb = gres + tb*16;
            bf16x8 g0 = *(const bf16x8*)gb;
            bf16x8 g1 = *(const bf16x8*)(gb + 8);
            #pragma unroll
            for (int i = 0; i < 16; i++) {
                float dlt = (float)(i < 8 ? d0[i] : d1[i-8]);
                float gr  = (float)(i < 8 ? g0[i] : g1[i-8]);
                float uu = __bfloat162float(*pu); pu += D_INNER;
                float du = dlt*uu;
                float e1 = fexp2(-dlt*LOG2E);
                float e = e1;
                float acc;
                xs[0] = e*xs[0] + du*pB[0];
                acc = xs[0]*pB[N_STATE + 0];
                #pragma unroll
                for (int n = 1; n < N_STATE; n++) {
                    e *= e1;
                    xs[n] = e*xs[n] + du*pB[n];
                    acc += xs[n]*pB[N_STATE + n];
                }
                pB += XN;
                float y = acc + uu*Dv;
                *py = __float2bfloat16(y * gr); py += D_INNER;
            }
        }
    } else {
        #pragma unroll
        for (int tt = 0; tt < 2; tt++) {
            size_t tb = (size_t)(b*NTILE + (l0>>4) + tt)*D_INNER + d;
            const __hip_bfloat16* db = delta_blk + tb*16;
            bf16x8 d0 = *(const bf16x8*)db;
            bf16x8 d1 = *(const bf16x8*)(db + 8);
            const __hip_bfloat16* gb = gres + tb*16;
            bf16x8 g0 = *(const bf16x8*)gb;
            bf16x8 g1 = *(const bf16x8*)(gb + 8);
            #pragma unroll
            for (int i = 0; i < 16; i++) {
                float dlt = (float)(i < 8 ? d0[i] : d1[i-8]);
                float gr  = (float)(i < 8 ? g0[i] : g1[i-8]);
                float uu = __bfloat162float(*pu); pu += D_INNER;
                float du = dlt*uu;
                float acc = 0.f;
                #pragma unroll
                for (int n = 0; n < N_STATE; n++) {
                    float A2n = -__expf(al[n]) * LOG2E;
                    xs[n] = fexp2(dlt*A2n)*xs[n] + du*pB[n];
                    acc += xs[n]*pB[N_STATE + n];
                }
                pB += XN;
                float y = acc + uu*Dv;
                *py = __float2bfloat16(y * gr); py += D_INNER;
            }
        }
    }
}

// ---------------------------------------------------------------- final norm + head + de-norm
__global__ __launch_bounds__(256) void final_kernel(const float* __restrict__ h,
                                                    const float* __restrict__ fnw,
                                                    const float* __restrict__ out_w,
                                                    const float* __restrict__ mean,
                                                    const float* __restrict__ stdv,
                                                    float* __restrict__ out) {
    int bid = blockIdx.x;
    int b = bid / PRED_LEN, lo = bid % PRED_LEN;
    int l = LSEQ - PRED_LEN + lo;
    const float* row = h + ((size_t)(b*LSEQ + l))*D_MODEL;
    __shared__ float tmp[4];
    float ss = 0.f;
    for (int k = threadIdx.x; k < D_MODEL; k += 256) { float v = row[k]; ss += v*v; }
    ss = block_sum(ss, tmp);
    float inv = rsqrtf(ss / (float)D_MODEL + EPSV);
    float acc[C_OUT] = {};
    for (int k = threadIdx.x; k < D_MODEL; k += 256) {
        float hn = row[k]*fnw[k];
        #pragma unroll
        for (int c = 0; c < C_OUT; c++) acc[c] += hn*out_w[c*D_MODEL + k];
    }
    #pragma unroll
    for (int c = 0; c < C_OUT; c++) {
        float s = block_sum(acc[c], tmp);
        if (threadIdx.x == 0)
            out[((size_t)(b*PRED_LEN + lo))*C_OUT + c] = s*inv*stdv[b*ENC_IN + c] + mean[b*ENC_IN + c];
    }
}

// ---------------------------------------------------------------- launch
extern "C" void kernel_launch(void* const* d_in, const int* in_sizes, int n_in,
                              void* d_out, int out_size, void* d_ws, size_t ws_size,
                              hipStream_t stream) {
    const float* x        = (const float*)d_in[0];
    const float* token_w  = (const float*)d_in[1];
    const float* time_w   = (const float*)d_in[2];
    const float* norm_w   = (const float*)d_in[3];
    const float* in_w     = (const float*)d_in[4];
    const float* conv_w   = (const float*)d_in[5];
    const float* conv_b   = (const float*)d_in[6];
    const float* xproj_w  = (const float*)d_in[7];
    const float* dtproj_w = (const float*)d_in[8];
    const float* dtproj_b = (const float*)d_in[9];
    const float* A_log    = (const float*)d_in[10];
    const float* Dp       = (const float*)d_in[11];
    const float* outproj_w= (const float*)d_in[12];
    const float* final_nw = (const float*)d_in[13];
    const float* out_w    = (const float*)d_in[14];
    float* out = (float*)d_out;

    float* ws   = (float*)d_ws;
    float* mean = ws;
    float* stdv = ws + 64;
    float* h    = ws + 128;                            // ROWS*D_MODEL
    float* xdbl = h    + (size_t)ROWS*D_MODEL;         // ROWS*80 f32
    float* sumd = xdbl + (size_t)ROWS*XN;              // BSZ*NC*D_INNER
    float* xfin = sumd + (size_t)BSZ*NC*D_INNER;       // BSZ*NC*N_STATE*D_INNER
    float* pout = xfin + (size_t)BSZ*NC*D_INNER*N_STATE; // KSPLIT*ROWS*XN partials
    float* fend = pout + (size_t)KSPLIT*ROWS*XN;
    __hip_bfloat16* xn_bf  = (__hip_bfloat16*)fend;
    __hip_bfloat16* xs_bf  = xn_bf + (size_t)ROWS*D_MODEL;
    __hip_bfloat16* u_bf   = xs_bf + (size_t)ROWS*D_INNER;
    __hip_bfloat16* gres   = u_bf  + (size_t)ROWS*D_INNER;
    __hip_bfloat16* ygate  = gres  + (size_t)ROWS*D_INNER;
    __hip_bfloat16* delta  = ygate + (size_t)ROWS*D_INNER;
    __hip_bfloat16* inwp   = delta + (size_t)ROWS*D_INNER;           // packed in_w
    __hip_bfloat16* outwp  = inwp  + (size_t)E_LAYERS*INP_LAYER;     // packed out_w
    __hip_bfloat16* xpw_bf = outwp + (size_t)E_LAYERS*OUTP_LAYER;
    __hip_bfloat16* dtw_bf = xpw_bf + (size_t)E_LAYERS*XN*D_INNER;

    {
        const int NT = E_LAYERS*XN*D_INNER + E_LAYERS*D_INNER*64
                     + E_LAYERS*INP_LAYER/8 + E_LAYERS*OUTP_LAYER/8;
        prep_all<<<(NT+255)/256, 256, 0, stream>>>(xproj_w, dtproj_w, in_w, outproj_w,
                                                   xpw_bf, dtw_bf, inwp, outwp);
    }

    stats_kernel<<<BSZ*ENC_IN, 256, 0, stream>>>(x, mean, stdv);
    embed_kernel<<<ROWS, 256, 0, stream>>>(x, token_w, time_w, mean, stdv, h);

    for (int e = 0; e < E_LAYERS; e++) {
        rmsnorm_bf16<<<ROWS, 256, 0, stream>>>(h, norm_w + e*D_MODEL, xn_bf);
        gemm_inproj<<<dim3(2*D_INNER/128, ROWS/128), 256, 0, stream>>>(
            xn_bf, inwp + (size_t)e*INP_LAYER, xs_bf, gres);
        dwconv_silu<<<(ROWS*(D_INNER/8) + 255)/256, 256, 0, stream>>>(
            xs_bf, conv_w + (size_t)e*D_INNER*K_CONV, conv_b + e*D_INNER, u_bf);
        gemm_xproj<<<dim3(ROWS/64, KSPLIT), 256, 0, stream>>>(
            u_bf, xpw_bf + (size_t)e*XN*D_INNER, pout);
        gemm_dtproj<<<dim3(D_INNER/128, ROWS/128), 256, 0, stream>>>(
            pout, dtw_bf + (size_t)e*D_INNER*64, dtproj_b + e*D_INNER, xdbl, delta);
        const float* Alog_e = A_log + (size_t)e*D_INNER*N_STATE;
        scan_p1<<<dim3(D_INNER/256, NC, BSZ), 256, 0, stream>>>(
            u_bf, delta, xdbl, Alog_e, xfin, sumd);
        scan_p2<<<(BSZ*D_INNER*N_STATE)/256, 256, 0, stream>>>(
            xfin, sumd, Alog_e);
        scan_p3<<<dim3(D_INNER/256, NC, BSZ), 256, 0, stream>>>(
            u_bf, delta, gres, xdbl, Alog_e, Dp + (size_t)e*D_INNER, xfin, ygate);
        gemm_outproj<<<dim3(D_MODEL/64, ROWS/128), 256, 0, stream>>>(
            ygate, outwp + (size_t)e*OUTP_LAYER, h);
    }

    final_kernel<<<BSZ*PRED_LEN, 256, 0, stream>>>(h, final_nw, out_w, mean, stdv, out);
}